// Round 3
// baseline (736.458 us; speedup 1.0000x reference)
//
#include <hip/hip_runtime.h>

// Hebbian plasticity update, B=2048 independent 128x128 problems — R3.
// Same MFMA math as R2 (verified), new schedule:
//  - 256 persistent blocks x 8 batches, software-pipelined
//  - raw s_barrier + manual lgkmcnt(0) (no vmcnt drain at barriers)
//  - reg-prefetch of obs/brim/was one phase ahead (T14)
//  - corr/reg round-trip through LDS as bf16 -> fully coalesced float4 epilogue

typedef __attribute__((ext_vector_type(8))) short bf16x8;
typedef __attribute__((ext_vector_type(4))) float f32x4;

constexpr int D   = 128;
constexpr int LDB = 136;   // bf16 operand-tile row stride (+8 pad)
constexpr int LDC = 132;   // bf16 corr/reg round-trip stride
constexpr int BPB = 8;     // batches per persistent block

__device__ __forceinline__ short f2bf(float x) {   // RNE fp32->bf16
    unsigned u = __builtin_bit_cast(unsigned, x);
    u += 0x7fff + ((u >> 16) & 1);
    return (short)(u >> 16);
}
__device__ __forceinline__ float bf2f(short s) {
    unsigned u = ((unsigned)(unsigned short)s) << 16;
    return __builtin_bit_cast(float, u);
}

// LDS-visibility barrier: drain DS ops, then raw s_barrier (vmcnt stays live).
#define LBAR() do { asm volatile("s_waitcnt lgkmcnt(0)" ::: "memory"); \
                    __builtin_amdgcn_s_barrier(); } while (0)

__global__ void cvt_weights(const float* __restrict__ kw,
                            const float* __restrict__ vw,
                            short* __restrict__ o) {
    int i = blockIdx.x * 256 + threadIdx.x;      // 16384 threads
    o[i]         = f2bf(kw[i]);
    o[16384 + i] = f2bf(vw[i]);
}

__global__ __launch_bounds__(512, 1)
void hebb_mfma(const float* __restrict__ obs,
               const float* __restrict__ brim,
               const float* __restrict__ modu,
               const float* __restrict__ was,
               const short* __restrict__ keyWb,
               const float* __restrict__ keyB,
               const short* __restrict__ valWb,
               const float* __restrict__ valB,
               const float* __restrict__ Aw,
               const float* __restrict__ Bw,
               const int* __restrict__ done,
               float* __restrict__ out)
{
    __shared__ __align__(16) short xS [D * LDB];   // staging: obs, then brim (bf16)
    __shared__ __align__(16) short kS [D * LDB];   // k bf16; later corr bf16 (stride LDC)
    __shared__ __align__(16) short kTS[D * LDB];   // kT bf16; later reg bf16 (stride LDC)
    __shared__ __align__(16) short vTS[D * LDB];   // vT bf16

    const int t  = threadIdx.x;
    const int w  = t >> 6;        // wave 0..7
    const int l  = t & 63;
    const int lr = l & 15;
    const int hg = l >> 4;
    const int b0 = blockIdx.x * BPB;

    // ---- hoisted bias fragments (constant across batches) ----
    float kbR[4], vbR[4], kbC[8], vbC[8];
    #pragma unroll
    for (int r = 0; r < 4; ++r) { kbR[r] = keyB[16*w + 4*hg + r]; vbR[r] = valB[16*w + 4*hg + r]; }
    #pragma unroll
    for (int q = 0; q < 8; ++q) { kbC[q] = keyB[16*q + lr]; vbC[q] = valB[16*q + lr]; }
    (void)vbC;

    // ---- prologue: prefetch obs[b0], brim[b0]; stage obs -> xS ----
    float4 obsR[8], brimR[8], wasR[8];
    {
        const float4* os = (const float4*)(obs  + (size_t)b0 * D * D);
        const float4* bs = (const float4*)(brim + (size_t)b0 * D * D);
        #pragma unroll
        for (int i = 0; i < 8; ++i) { obsR[i] = os[i*512 + t]; brimR[i] = bs[i*512 + t]; }
    }
    #pragma unroll
    for (int i = 0; i < 8; ++i) {
        int f = (i * 512 + t) * 4;
        int row = f >> 7, col = f & 127;
        *(short4*)&xS[row * LDB + col] =
            make_short4(f2bf(obsR[i].x), f2bf(obsR[i].y), f2bf(obsR[i].z), f2bf(obsR[i].w));
    }
    LBAR();

    for (int it = 0; it < BPB; ++it) {
        const int b  = b0 + it;
        const size_t ob = (size_t)b * D * D;

        // ================= P1b: k (A=obs,B=keyW) and kT (A=keyW,B=obs) =================
        f32x4 acc[8], acc2[8];
        #pragma unroll
        for (int i = 0; i < 8; ++i) { acc[i] = f32x4{0.f,0.f,0.f,0.f}; acc2[i] = f32x4{0.f,0.f,0.f,0.f}; }

        for (int c = 0; c < 4; ++c) {
            const int c0 = c * 32 + 8 * hg;
            bf16x8 aK = *(const bf16x8*)&xS[(16*w + lr) * LDB + c0];
            bf16x8 aT = *(const bf16x8*)&keyWb[(16*w + lr) * D + c0];
            #pragma unroll
            for (int q = 0; q < 8; ++q) {
                bf16x8 bK = *(const bf16x8*)&keyWb[(16*q + lr) * D + c0];
                bf16x8 bT = *(const bf16x8*)&xS[(16*q + lr) * LDB + c0];
                acc[q]  = __builtin_amdgcn_mfma_f32_16x16x32_bf16(aK, bK, acc[q],  0, 0, 0);
                acc2[q] = __builtin_amdgcn_mfma_f32_16x16x32_bf16(aT, bT, acc2[q], 0, 0, 0);
            }
        }
        #pragma unroll
        for (int q = 0; q < 8; ++q) {
            #pragma unroll
            for (int r = 0; r < 4; ++r) {
                kS [(16*w + 4*hg + r) * LDB + 16*q + lr] = f2bf(acc[q][r]  + kbC[q]);
                kTS[(16*w + 4*hg + r) * LDB + 16*q + lr] = f2bf(acc2[q][r] + kbR[r]);
            }
        }
        LBAR();   // B1: all xS(obs) reads done; kS/kTS in flight to P2

        // ---- stage brim -> xS (regs prefetched last iter); issue was[b] ----
        #pragma unroll
        for (int i = 0; i < 8; ++i) {
            int f = (i * 512 + t) * 4;
            int row = f >> 7, col = f & 127;
            *(short4*)&xS[row * LDB + col] =
                make_short4(f2bf(brimR[i].x), f2bf(brimR[i].y), f2bf(brimR[i].z), f2bf(brimR[i].w));
        }
        {
            const float4* ws = (const float4*)(was + ob);
            #pragma unroll
            for (int ci = 0; ci < 8; ++ci) wasR[ci] = ws[ci*512 + t];
        }
        LBAR();   // B2: xS = brim visible

        // ================= P1d: vT (A=valW, B=brim), neuromodulated =================
        float mq[8];
        #pragma unroll
        for (int q = 0; q < 8; ++q) mq[q] = modu[(size_t)b * D + 16*q + lr];

        f32x4 vacc[8];
        #pragma unroll
        for (int i = 0; i < 8; ++i) vacc[i] = f32x4{0.f,0.f,0.f,0.f};
        for (int c = 0; c < 4; ++c) {
            const int c0 = c * 32 + 8 * hg;
            bf16x8 aV = *(const bf16x8*)&valWb[(16*w + lr) * D + c0];
            #pragma unroll
            for (int q = 0; q < 8; ++q) {
                bf16x8 bV = *(const bf16x8*)&xS[(16*q + lr) * LDB + c0];
                vacc[q] = __builtin_amdgcn_mfma_f32_16x16x32_bf16(aV, bV, vacc[q], 0, 0, 0);
            }
        }
        #pragma unroll
        for (int q = 0; q < 8; ++q) {
            #pragma unroll
            for (int r = 0; r < 4; ++r)
                vTS[(16*w + 4*hg + r) * LDB + 16*q + lr] = f2bf(mq[q] * (vacc[q][r] + vbR[r]));
        }
        LBAR();   // B3: vTS visible

        // ================= P2: corr & reg; prefetch obs[next] under MFMAs =================
        if (it < BPB - 1) {
            const float4* os = (const float4*)(obs + (size_t)(b + 1) * D * D);
            #pragma unroll
            for (int i = 0; i < 8; ++i) obsR[i] = os[i*512 + t];
        }
        f32x4 cacc[8], racc[8];
        #pragma unroll
        for (int i = 0; i < 8; ++i) { cacc[i] = f32x4{0.f,0.f,0.f,0.f}; racc[i] = f32x4{0.f,0.f,0.f,0.f}; }

        for (int c = 0; c < 4; ++c) {
            const int c0 = c * 32 + 8 * hg;
            bf16x8 aC = *(const bf16x8*)&kTS[(16*w + lr) * LDB + c0];
            bf16x8 aR = *(const bf16x8*)&kS [(16*w + lr) * LDB + c0];
            #pragma unroll
            for (int q = 0; q < 8; ++q) {
                bf16x8 bC = *(const bf16x8*)&vTS[(16*q + lr) * LDB + c0];
                bf16x8 bR = *(const bf16x8*)&kTS[(16*q + lr) * LDB + c0];
                cacc[q] = __builtin_amdgcn_mfma_f32_16x16x32_bf16(aC, bC, cacc[q], 0, 0, 0);
                racc[q] = __builtin_amdgcn_mfma_f32_16x16x32_bf16(aR, bR, racc[q], 0, 0, 0);
            }
        }
        LBAR();   // B4: all P2 LDS reads drained -> safe to overwrite kS/kTS

        // ---- round-trip corr/reg as bf16 into kS/kTS (stride LDC) ----
        #pragma unroll
        for (int q = 0; q < 8; ++q) {
            #pragma unroll
            for (int r = 0; r < 4; ++r) {
                kS [(16*w + 4*hg + r) * LDC + 16*q + lr] = f2bf(cacc[q][r]);
                kTS[(16*w + 4*hg + r) * LDC + 16*q + lr] = f2bf(racc[q][r]);
            }
        }
        LBAR();   // B5: corr/reg visible

        // ================= epilogue: coalesced float4 combine =================
        const float dsc = done[b] ? 1.0f : 0.0f;
        #pragma unroll
        for (int ci = 0; ci < 8; ++ci) {
            const int row = 16*ci + (t >> 5);
            const int j0  = (t & 31) * 4;
            short4 cs = *(const short4*)&kS [row * LDC + j0];
            short4 rs = *(const short4*)&kTS[row * LDC + j0];
            float4 w4 = wasR[ci];
            float4 a4 = *(const float4*)&Aw[row * D + j0];
            float4 b4 = *(const float4*)&Bw[row * D + j0];
            float4 o;
            o.x = w4.x + dsc * (a4.x * (1.f - w4.x) * bf2f(cs.x) - b4.x * w4.x * bf2f(rs.x));
            o.y = w4.y + dsc * (a4.y * (1.f - w4.y) * bf2f(cs.y) - b4.y * w4.y * bf2f(rs.y));
            o.z = w4.z + dsc * (a4.z * (1.f - w4.z) * bf2f(cs.z) - b4.z * w4.z * bf2f(rs.z));
            o.w = w4.w + dsc * (a4.w * (1.f - w4.w) * bf2f(cs.w) - b4.w * w4.w * bf2f(rs.w));
            *(float4*)&out[ob + row * D + j0] = o;
        }

        // ---- stage obs[next] -> xS; issue brim[next] ----
        if (it < BPB - 1) {
            #pragma unroll
            for (int i = 0; i < 8; ++i) {
                int f = (i * 512 + t) * 4;
                int row = f >> 7, col = f & 127;
                *(short4*)&xS[row * LDB + col] =
                    make_short4(f2bf(obsR[i].x), f2bf(obsR[i].y), f2bf(obsR[i].z), f2bf(obsR[i].w));
            }
            const float4* bs = (const float4*)(brim + (size_t)(b + 1) * D * D);
            #pragma unroll
            for (int i = 0; i < 8; ++i) brimR[i] = bs[i*512 + t];
        }
        LBAR();   // B6: xS = obs[next] visible
    }
}

extern "C" void kernel_launch(void* const* d_in, const int* in_sizes, int n_in,
                              void* d_out, int out_size, void* d_ws, size_t ws_size,
                              hipStream_t stream) {
    const float* obs  = (const float*)d_in[0];
    const float* brim = (const float*)d_in[1];
    const float* modu = (const float*)d_in[2];
    const float* was  = (const float*)d_in[3];
    const float* keyW = (const float*)d_in[4];
    const float* keyB = (const float*)d_in[5];
    const float* valW = (const float*)d_in[6];
    const float* valB = (const float*)d_in[7];
    const float* Aw   = (const float*)d_in[8];
    const float* Bw   = (const float*)d_in[9];
    const int*   done = (const int*)d_in[10];
    float* out = (float*)d_out;

    const int B = in_sizes[10];                 // 2048 batches
    short* wb = (short*)d_ws;                   // [0,32K): keyW bf16, [32K,64K): valW bf16

    hipLaunchKernelGGL(cvt_weights, dim3(64), dim3(256), 0, stream, keyW, valW, wb);
    hipLaunchKernelGGL(hebb_mfma, dim3(B / BPB), dim3(512), 0, stream,
                       obs, brim, modu, was, wb, keyB, wb + 16384, valB,
                       Aw, Bw, done, out);
}